// Round 9
// baseline (424.200 us; speedup 1.0000x reference)
//
#include <hip/hip_runtime.h>
#include <hip/hip_bf16.h>
#include <math.h>

typedef __bf16 bf16;
typedef __bf16 bf16x4 __attribute__((ext_vector_type(4)));
typedef __bf16 bf16x8 __attribute__((ext_vector_type(8)));
typedef float f32x4 __attribute__((ext_vector_type(4)));
typedef unsigned int u32;
typedef u32 __attribute__((address_space(1))) gu32;
typedef u32 __attribute__((address_space(3))) lu32;

#define TOK   16384
#define D_    256
#define HD    2048
#define VN    2048

#define GLDS16(g, l) __builtin_amdgcn_global_load_lds((gu32*)(g), (lu32*)(l), 16, 0, 0)
// s_waitcnt imm: vmcnt[3:0]|[15:14] | expcnt<<4 | lgkmcnt<<8
#define WAIT_VM(n)  __builtin_amdgcn_s_waitcnt(0x0F70 | (n))   // lgkm=15(no), exp=7(no), vm=n (LITERAL)
#define WAIT_LGKM0  __builtin_amdgcn_s_waitcnt(0xC07F)          // vm=63(no), exp=7(no), lgkm=0
#define BAR() do { __builtin_amdgcn_s_barrier(); __builtin_amdgcn_sched_barrier(0); } while (0)
#define SCHEDFENCE() __builtin_amdgcn_sched_barrier(0)

// ---------------------------------------------------------------------------
// prep: roles by blockIdx.x. Dtype flag computed block-locally. (unchanged)
//   b <  4096: convert x
//   b <  4121: biases -> bqkv (WTI-row order), bo -> bob
//   b <  5657: Wq/Wk/Wv transpose into WTI (6144 rows x 256 K):
//              q: row = (d>>3)*128 +      h*8 + (d&7)   (d-block-of-8 interleave)
//              k: row = (d>>3)*128 + 64 + h*8 + (d&7)
//              v: row = 4096 + d*8 + h                  (d-major)
//   b <  6169: Wo transpose (K permuted d-major) -> WoT
// ---------------------------------------------------------------------------
__device__ __forceinline__ void transpose_body(
    const void* __restrict__ src, bf16* __restrict__ dst, int R, int C,
    int tc, int tr, int f, int mode, float (*tile)[33])
{
    int lx = threadIdx.x & 31, ly = threadIdx.x >> 5;
    for (int i = 0; i < 4; i++) {
        int r = ly + i * 8;
        size_t idx = (size_t)(tr + r) * C + tc + lx;
        tile[r][lx] = f ? ((const float*)src)[idx] : (float)((const bf16*)src)[idx];
    }
    __syncthreads();
    for (int i = 0; i < 4; i++) {
        int r = ly + i * 8;
        int k = tr + lx;                     // source row = K index
        int n = tc + r;                      // source col = output row
        size_t di;
        if (mode == 1)
            di = (size_t)n * 2048 + ((k & 255) << 3) + (k >> 8);
        else if (mode == 2)
            di = (size_t)(4096 + ((n & 255) << 3) + (n >> 8)) * 256 + k;
        else if (mode == 3)
            di = (size_t)((((n & 255) >> 3) << 7) + ((n >> 8) << 3) + (n & 7)) * 256 + k;
        else if (mode == 4)
            di = (size_t)((((n & 255) >> 3) << 7) + 64 + ((n >> 8) << 3) + (n & 7)) * 256 + k;
        else
            di = (size_t)n * R + k;
        dst[di] = (bf16)tile[lx][r];
    }
}

__global__ __launch_bounds__(256) void prep(
    const void* __restrict__ x,
    const void* __restrict__ Wq, const void* __restrict__ bq,
    const void* __restrict__ Wk, const void* __restrict__ bk,
    const void* __restrict__ Wv, const void* __restrict__ bv,
    const void* __restrict__ Wo, const void* __restrict__ bo,
    bf16* __restrict__ xb, bf16* __restrict__ WTI, bf16* __restrict__ WoT,
    bf16* __restrict__ bqkv, bf16* __restrict__ bob)
{
    __shared__ float tile[32][33];
    __shared__ int sflag;
    int tid = threadIdx.x;
    if (tid == 0) sflag = 0;
    __syncthreads();
    {
        float v = fabsf((float)((const bf16*)x)[2 * tid]);
        if (!(v < 1e4f)) sflag = 1;   // benign race, all writers store 1
    }
    __syncthreads();
    int f = sflag;
    int b = blockIdx.x;

    if (b < 4096) {                               // convert x
        int i = b * 256 + tid;
        bf16x4 o;
        if (f) { f32x4 v = ((const f32x4*)x)[i]; for (int e = 0; e < 4; e++) o[e] = (bf16)v[e]; }
        else   { o = ((const bf16x4*)x)[i]; }
        ((bf16x4*)xb)[i] = o;
    } else if (b < 4121) {                        // biases (WTI-row order)
        int i = (b - 4096) * 256 + tid;
        if (i < 6400) {
            const void* src; bf16* dst = bqkv; int off, woff;
            if (i < 2048) {
                src = bq; off = i;
                int d = off & 255, h = off >> 8;
                woff = ((d >> 3) << 7) + (h << 3) + (d & 7);
            } else if (i < 4096) {
                src = bk; off = i - 2048;
                int d = off & 255, h = off >> 8;
                woff = ((d >> 3) << 7) + 64 + (h << 3) + (d & 7);
            } else if (i < 6144) {
                src = bv; off = i - 4096;
                woff = 4096 + ((off & 255) << 3) + (off >> 8);
            } else {
                src = bo; dst = bob; off = i - 6144; woff = off;
            }
            float v = f ? ((const float*)src)[off] : (float)((const bf16*)src)[off];
            dst[woff] = (bf16)v;
        }
        __syncthreads();                          // match transpose barrier count
    } else if (b < 5657) {                        // Wq/Wk/Wv -> WTI
        int idx = b - 4121;                       // 0..1535
        int tx = idx & 63, rest = idx >> 6;
        int ty = rest & 7, tz = rest >> 3;
        const void* src = (tz == 0) ? Wq : (tz == 1) ? Wk : Wv;
        int mode = (tz == 0) ? 3 : (tz == 1) ? 4 : 2;
        transpose_body(src, WTI, 256, 2048, tx * 32, ty * 32, f, mode, tile);
    } else {                                      // Wo -> WoT (K d-major)
        int idx = b - 5657;                       // 0..511
        int tx = idx & 7, ty = idx >> 3;
        transpose_body(Wo, WoT, 2048, 256, tx * 32, ty * 32, f, 1, tile);
    }
}

// ---------------------------------------------------------------------------
// Kernel 1: v = x @ Wv + bv  (d-major cols). Verified kernel, unchanged.
// ---------------------------------------------------------------------------
__global__ __launch_bounds__(256) void v_proj(
    const bf16* __restrict__ X, const bf16* __restrict__ WT,
    const bf16* __restrict__ bI, bf16* __restrict__ vout)
{
    __shared__ char smem[36864];               // union: As+Bs (32K) / epi (36K)
    bf16* As = (bf16*)smem;                    // 128*64
    bf16* Bs = (bf16*)(smem + 16384);          // 128*64
    int m0 = blockIdx.y * 128, n0 = blockIdx.x * 128;
    int tid = threadIdx.x, wave = tid >> 6, lane = tid & 63;
    int wm = (wave >> 1) * 64, wn = (wave & 1) * 64;
    int mrow = lane & 15, quad = lane >> 4;
    int lrow8 = lane >> 3, lslot = lane & 7;

    f32x4 acc[4][4] = {};
    for (int k0 = 0; k0 < D_; k0 += 64) {
        __syncthreads();
        for (int i = 0; i < 4; i++) {
            int rbase = wave * 32 + i * 8;
            int row = rbase + lrow8;
            int gc = lslot ^ (row & 7);
            GLDS16(&X[(size_t)(m0 + row) * D_ + k0 + gc * 8], &As[rbase * 64]);
            GLDS16(&WT[(size_t)(n0 + row) * D_ + k0 + gc * 8], &Bs[rbase * 64]);
        }
        __syncthreads();
        for (int kk = 0; kk < 64; kk += 32) {
            int slot = (((kk >> 3) + quad) ^ (mrow & 7)) * 8;
            bf16x8 af[4], bfv[4];
            for (int mt = 0; mt < 4; mt++)
                af[mt] = *(const bf16x8*)&As[(wm + mt * 16 + mrow) * 64 + slot];
            for (int nt = 0; nt < 4; nt++)
                bfv[nt] = *(const bf16x8*)&Bs[(wn + nt * 16 + mrow) * 64 + slot];
            for (int mt = 0; mt < 4; mt++)
                for (int nt = 0; nt < 4; nt++)
                    acc[mt][nt] = __builtin_amdgcn_mfma_f32_16x16x32_bf16(
                        bfv[nt], af[mt], acc[mt][nt], 0, 0, 0);
        }
    }

    __syncthreads();
    bf16* ep = (bf16*)smem + wave * (64 * 72);
    for (int mt = 0; mt < 4; mt++) {
        for (int nt = 0; nt < 4; nt++) {
            int col = n0 + wn + nt * 16 + quad * 4;
            bf16x4 bb = *(const bf16x4*)&bI[col];
            bf16x4 o;
            for (int r = 0; r < 4; r++) o[r] = (bf16)(acc[mt][nt][r] + (float)bb[r]);
            *(bf16x4*)&ep[(mt * 16 + mrow) * 72 + nt * 16 + quad * 4] = o;
        }
    }
    __syncthreads();
    for (int i = 0; i < 8; i++) {
        int r = i * 8 + (lane >> 3);
        int cb = (lane & 7) * 8;
        bf16x8 val = *(const bf16x8*)&ep[r * 72 + cb];
        *(bf16x8*)&vout[(size_t)(m0 + wm + r) * VN + n0 + wn + cb] = val;
    }
}

// ---------------------------------------------------------------------------
// Kernel 2: q/k projection + per-token 8x8 raw scores -> Sbuf.  v5 (from r8):
//  - grid 512: block = 64 tokens x HALF the d-range (dh = bid&1, 16 d-blocks)
//    -> per-CU work unchanged, but 2 ANTI-PHASE blocks/CU fill each other's
//    barrier/DMA stalls (r8 was 1 block/CU at 145 KB, 55% stall)
//  - LDS 80 KB exactly: Ws single 8KB/wave (wave-private, lgkm-drained
//    before restage, DMA hides under MFMA+epi+score+2 BAR) + qkh [64][128]
//    with granule-XOR swizzle g8^=(t&7)<<1 (write+read; epi 2-way/free,
//    score reads hit 32 banks exactly once, b128 contiguity kept)
//  - softmax moved to out_fused; S partials (f32) written per d-half
// ---------------------------------------------------------------------------
__global__ __launch_bounds__(512, 4) void qk_score(
    const bf16* __restrict__ X, const bf16* __restrict__ WTI,
    const bf16* __restrict__ bI, float* __restrict__ Sbuf)
{
    __shared__ bf16 Ws[8][16 * 256];      // 64 KB: per-wave single-buffer B
    __shared__ bf16 qkh[64 * 128];        // 16 KB: granule-XOR swizzled
    int tid = threadIdx.x, wave = tid >> 6, lane = tid & 63;
    int mrow = lane & 15, quad = lane >> 4;
    int h = lane >> 3, g = lane & 7;
    int bid = blockIdx.x;
    int t0 = (bid >> 1) * 64;
    int dh = bid & 1;                     // d-half: d-blocks dh*16 .. dh*16+15
    bf16* wsbase = &Ws[0][0];

    // ---- prologue: x-tile 64x256 -> first 32KB of Ws (cooperative) ----
#pragma unroll
    for (int i = 0; i < 4; i++) {
        int row = (i * 8 + wave) * 2 + (lane >> 5);
        int sl = lane & 31;
        int gc = (sl & 24) | ((sl & 7) ^ (row & 7));
        GLDS16(&X[(size_t)(t0 + row) * 256 + gc * 8], &wsbase[(i * 8 + wave) * 512]);
    }
    WAIT_VM(0);
    BAR();
    bf16x8 areg[4][8];                    // all 64 tokens, K=256
#pragma unroll
    for (int mt = 0; mt < 4; mt++)
#pragma unroll
        for (int ks = 0; ks < 8; ks++) {
            int arow = mt * 16 + mrow;
            int sl = ks * 4 + quad;
            int ph = (sl & 24) | ((sl & 7) ^ (arow & 7));
            areg[mt][ks] = *(const bf16x8*)&wsbase[arow * 256 + ph * 8];
        }
    WAIT_LGKM0;                           // A lifts retired before Ws reuse
    BAR();

    bf16* wsw = &Ws[wave][0];             // this wave's private 8KB buffer
    const bf16* wsrc = WTI + (size_t)(wave * 16) * 256;
#define QK_STAGE(GIT) {                                                        \
        const bf16* s_ = wsrc + (size_t)(GIT) * 32768;                         \
        _Pragma("unroll")                                                      \
        for (int j = 0; j < 8; j++) {                                          \
            int row = j * 2 + (lane >> 5);                                     \
            int sl = lane & 31;                                                \
            int gc = (sl & 24) | ((sl & 7) ^ (row & 7));                       \
            GLDS16(&s_[(size_t)row * 256 + gc * 8], &wsw[j * 512]);            \
        } }
    QK_STAGE(dh * 16)

    float S[8] = {};

    for (int it = 0; it < 16; it++) {
        int git = dh * 16 + it;
        WAIT_VM(0);                        // my 8 DMAs for subtile git done
        bf16x8 bvv[8];
#pragma unroll
        for (int ks = 0; ks < 8; ks++) {
            int sl = ks * 4 + quad;
            int ph = (sl & 24) | ((sl & 7) ^ (mrow & 7));
            bvv[ks] = *(const bf16x8*)&wsw[mrow * 256 + ph * 8];
        }
        WAIT_LGKM0;                        // bvv in regs -> buffer free for DMA
        SCHEDFENCE();
        if (it < 15) QK_STAGE(git + 1)

        f32x4 acc[4] = {};
#pragma unroll
        for (int ks = 0; ks < 8; ks++)
#pragma unroll
            for (int mt = 0; mt < 4; mt++)
                acc[mt] = __builtin_amdgcn_mfma_f32_16x16x32_bf16(
                    bvv[ks], areg[mt][ks], acc[mt], 0, 0, 0);

        // epilogue -> qkh: token t = mt*16+mrow, granule (wave*4+quad)^((t&7)<<1)
        bf16x4 bb = *(const bf16x4*)&bI[git * 128 + wave * 16 + quad * 4];
#pragma unroll
        for (int mt = 0; mt < 4; mt++) {
            int t = mt * 16 + mrow;
            bf16x4 o;
#pragma unroll
            for (int r = 0; r < 4; r++) o[r] = (bf16)(acc[mt][r] + (float)bb[r]);
            int g8 = (wave * 4 + quad) ^ ((t & 7) << 1);
            *(bf16x4*)((char*)qkh + t * 256 + g8 * 8) = o;
        }
        WAIT_LGKM0;                        // epi writes committed
        BAR();                             // qkh(it) published to all waves

        // score accumulate: wave owns tokens wave*8..+7; broadcast reads,
        // swizzled granules cover all 32 banks exactly once
#pragma unroll
        for (int u = 0; u < 8; u++) {
            int t = wave * 8 + u;
            int s = (t & 7) << 1;
            const char* base = (const char*)qkh + t * 256;
            bf16x8 qv = *(const bf16x8*)(base + ((h * 2) ^ s) * 8);
            bf16x8 kv = *(const bf16x8*)(base + ((16 + g * 2) ^ s) * 8);
            float a = 0.f;
#pragma unroll
            for (int e = 0; e < 8; e++) a += (float)qv[e] * (float)kv[e];
            S[u] += a;
        }
        WAIT_LGKM0;                        // score reads retired
        BAR();                             // before next iter's epi rewrites qkh
    }
#undef QK_STAGE

    // ---- raw partial scores out (softmax happens in out_fused) ----
#pragma unroll
    for (int u = 0; u < 8; u++) {
        int t = t0 + wave * 8 + u;
        Sbuf[(size_t)dh * TOK * 64 + (size_t)t * 64 + lane] = S[u];
    }
}

// ---------------------------------------------------------------------------
// Kernel 3: out = softmax((S0+S1)/16) @ v @ Wo' + bo.  Verified r5 kernel;
// only the Pv load changed: sum the two d-half score partials, apply scale,
// in-lane softmax (lane holds its token's full 64-entry row; softmax is over
// g within each h-group of 8 -> no cross-lane traffic). ~500 VALU cyc once.
// ---------------------------------------------------------------------------
__global__ __launch_bounds__(256) void out_fused(
    const bf16* __restrict__ vb, const bf16* __restrict__ WoT,
    const float* __restrict__ Sbuf, const bf16* __restrict__ bob,
    float* __restrict__ outp)
{
    __shared__ bf16 Bs[2][256 * 64];   // 64 KB  Wo' chunk (double)
    __shared__ bf16 Vs[2][32 * 64];    // 8 KB   v chunk (double)
    int m0 = blockIdx.x * 32;
    int tid = threadIdx.x, wave = tid >> 6, lane = tid & 63;
    int wm = (wave >> 1) * 16, wn = (wave & 1) * 128;
    int mrow = lane & 15, quad = lane >> 4;
    int t = wm + mrow, ts = t & 7;
    int sl8 = lane >> 3, sl = lane & 7;

    float Pv[64];
    {
        const float* p0 = Sbuf + (size_t)(m0 + t) * 64;
        const float* p1 = p0 + (size_t)TOK * 64;
#pragma unroll
        for (int j = 0; j < 16; j++) {
            f32x4 a = *(const f32x4*)&p0[j * 4];
            f32x4 b = *(const f32x4*)&p1[j * 4];
            for (int e = 0; e < 4; e++) Pv[4 * j + e] = (a[e] + b[e]) * 0.0625f;
        }
#pragma unroll
        for (int hh = 0; hh < 8; hh++) {
            float m = Pv[hh * 8];
            for (int e = 1; e < 8; e++) m = fmaxf(m, Pv[hh * 8 + e]);
            float sum = 0.f;
            for (int e = 0; e < 8; e++) {
                float p = __expf(Pv[hh * 8 + e] - m);
                Pv[hh * 8 + e] = p;
                sum += p;
            }
            float inv = 1.f / sum;
            for (int e = 0; e < 8; e++) Pv[hh * 8 + e] *= inv;
        }
    }

    f32x4 acc[8] = {};
    {   // prologue: stage chunk 0
        int tt = (wave << 3) + sl8;
        GLDS16(&vb[(size_t)(m0 + tt) * VN + ((sl ^ (tt & 7)) << 3)],
               &Vs[0][wave * 512]);
#pragma unroll
        for (int i = 0; i < 8; i++) {
            int n = (wave << 6) + (i << 3) + sl8;
            GLDS16(&WoT[(size_t)n * HD + ((sl ^ (n & 7)) << 3)],
                   &Bs[0][((wave << 6) + (i << 3)) << 6]);
        }
    }

    for (int c = 0; c < 32; c++) {
        __syncthreads();               // buf[c&1] resident (barrier drains vmcnt)
        if (c < 31) {
            int cc = c + 1, bb = cc & 1;
            int tt = (wave << 3) + sl8;
            GLDS16(&vb[(size_t)(m0 + tt) * VN + cc * 64 + ((sl ^ (tt & 7)) << 3)],
                   &Vs[bb][wave * 512]);
#pragma unroll
            for (int i = 0; i < 8; i++) {
                int n = (wave << 6) + (i << 3) + sl8;
                GLDS16(&WoT[(size_t)n * HD + cc * 64 + ((sl ^ (n & 7)) << 3)],
                       &Bs[bb][((wave << 6) + (i << 3)) << 6]);
            }
        }
        const bf16* Vb = Vs[c & 1];
        const bf16* Bb = Bs[c & 1];

        bf16x8 vf0 = *(const bf16x8*)&Vb[(t << 6) + ((quad ^ ts) << 3)];
        bf16x8 vf1 = *(const bf16x8*)&Vb[(t << 6) + (((quad + 4) ^ ts) << 3)];
        float v0f[8], v1f[8];
#pragma unroll
        for (int e = 0; e < 8; e++) { v0f[e] = (float)vf0[e]; v1f[e] = (float)vf1[e]; }
        bf16x8 af0, af1;
#pragma unroll
        for (int hh = 0; hh < 8; hh++) {
            float a0 = 0.f, a1 = 0.f;
#pragma unroll
            for (int gg = 0; gg < 8; gg++) {
                a0 += Pv[hh * 8 + gg] * v0f[gg];
                a1 += Pv[hh * 8 + gg] * v1f[gg];
            }
            af0[hh] = (bf16)a0; af1[hh] = (bf16)a1;
        }
#pragma unroll
        for (int nt = 0; nt < 8; nt++) {
            bf16x8 bv = *(const bf16x8*)&Bb[(wn + nt * 16 + mrow) * 64
                            + ((quad ^ (mrow & 7)) << 3)];
            acc[nt] = __builtin_amdgcn_mfma_f32_16x16x32_bf16(bv, af0, acc[nt], 0, 0, 0);
        }
#pragma unroll
        for (int nt = 0; nt < 8; nt++) {
            bf16x8 bv = *(const bf16x8*)&Bb[(wn + nt * 16 + mrow) * 64
                            + (((4 + quad) ^ (mrow & 7)) << 3)];
            acc[nt] = __builtin_amdgcn_mfma_f32_16x16x32_bf16(bv, af1, acc[nt], 0, 0, 0);
        }
    }

    int row = m0 + wm + mrow;
#pragma unroll
    for (int nt = 0; nt < 8; nt++) {
        int col = wn + nt * 16 + quad * 4;
        bf16x4 bb = *(const bf16x4*)&bob[col];
        f32x4 o;
        for (int r = 0; r < 4; r++) o[r] = acc[nt][r] + (float)bb[r];
        *(f32x4*)&outp[(size_t)row * D_ + col] = o;
    }
}

// ---------------------------------------------------------------------------
extern "C" void kernel_launch(void* const* d_in, const int* in_sizes, int n_in,
                              void* d_out, int out_size, void* d_ws, size_t ws_size,
                              hipStream_t stream)
{
    const void* x  = d_in[0];
    const void* Wq = d_in[1];
    const void* bq = d_in[2];
    const void* Wk = d_in[3];
    const void* bk = d_in[4];
    const void* Wv = d_in[5];
    const void* bv = d_in[6];
    const void* Wo = d_in[7];
    const void* bo = d_in[8];
    float* out = (float*)d_out;

    char* ws = (char*)d_ws;
    bf16*  vbuf = (bf16*)ws;                      // 16384*2048*2 = 67108864
    bf16*  WTI  = (bf16*)(ws + 67108864);         // 6144*256*2   = 3145728
    bf16*  WoT  = (bf16*)(ws + 70254592);         // 256*2048*2   = 1048576
    bf16*  xb   = (bf16*)(ws + 71303168);         // 16384*256*2  = 8388608
    bf16*  bqkv = (bf16*)(ws + 79691776);         // 6144*2       = 12288
    bf16*  bob  = (bf16*)(ws + 79704064);         // 512
    float* Sbuf = (float*)(ws + 79704576);        // 2*16384*64*4 = 8388608

    prep<<<6169, 256, 0, stream>>>(x, Wq, bq, Wk, bk, Wv, bv, Wo, bo,
                                   xb, WTI, WoT, bqkv, bob);
    qk_score<<<512, 512, 0, stream>>>(xb, WTI, bqkv, Sbuf);
    v_proj<<<dim3(16, 128), 256, 0, stream>>>(xb, WTI + 4096 * 256, bqkv + 4096, vbuf);
    out_fused<<<512, 256, 0, stream>>>(vbuf, WoT, Sbuf, bob, out);
}

// Round 10
// 281.499 us; speedup vs baseline: 1.5069x; 1.5069x over previous
//
#include <hip/hip_runtime.h>
#include <hip/hip_bf16.h>
#include <math.h>

typedef __bf16 bf16;
typedef __bf16 bf16x4 __attribute__((ext_vector_type(4)));
typedef __bf16 bf16x8 __attribute__((ext_vector_type(8)));
typedef float f32x4 __attribute__((ext_vector_type(4)));
typedef unsigned int u32;
typedef u32 __attribute__((address_space(1))) gu32;
typedef u32 __attribute__((address_space(3))) lu32;

#define TOK   16384
#define D_    256
#define HD    2048
#define VN    2048

#define GLDS16(g, l) __builtin_amdgcn_global_load_lds((gu32*)(g), (lu32*)(l), 16, 0, 0)
// s_waitcnt imm: vmcnt[3:0]|[15:14] | expcnt<<4 | lgkmcnt<<8
#define WAIT_VM(n)  __builtin_amdgcn_s_waitcnt(0x0F70 | (n))   // lgkm=15(no), exp=7(no), vm=n (LITERAL)
#define WAIT_LGKM0  __builtin_amdgcn_s_waitcnt(0xC07F)          // vm=63(no), exp=7(no), lgkm=0
#define BAR() do { __builtin_amdgcn_s_barrier(); __builtin_amdgcn_sched_barrier(0); } while (0)
#define SCHEDFENCE() __builtin_amdgcn_sched_barrier(0)

// ---------------------------------------------------------------------------
// prep: roles by blockIdx.x. Dtype flag computed block-locally. (unchanged)
//   b <  4096: convert x
//   b <  4121: biases -> bqkv (WTI-row order), bo -> bob
//   b <  5657: Wq/Wk/Wv transpose into WTI (6144 rows x 256 K):
//              q: row = (d>>3)*128 +      h*8 + (d&7)   (d-block-of-8 interleave)
//              k: row = (d>>3)*128 + 64 + h*8 + (d&7)
//              v: row = 4096 + d*8 + h                  (d-major)
//   b <  6169: Wo transpose (K permuted d-major) -> WoT
// ---------------------------------------------------------------------------
__device__ __forceinline__ void transpose_body(
    const void* __restrict__ src, bf16* __restrict__ dst, int R, int C,
    int tc, int tr, int f, int mode, float (*tile)[33])
{
    int lx = threadIdx.x & 31, ly = threadIdx.x >> 5;
    for (int i = 0; i < 4; i++) {
        int r = ly + i * 8;
        size_t idx = (size_t)(tr + r) * C + tc + lx;
        tile[r][lx] = f ? ((const float*)src)[idx] : (float)((const bf16*)src)[idx];
    }
    __syncthreads();
    for (int i = 0; i < 4; i++) {
        int r = ly + i * 8;
        int k = tr + lx;                     // source row = K index
        int n = tc + r;                      // source col = output row
        size_t di;
        if (mode == 1)
            di = (size_t)n * 2048 + ((k & 255) << 3) + (k >> 8);
        else if (mode == 2)
            di = (size_t)(4096 + ((n & 255) << 3) + (n >> 8)) * 256 + k;
        else if (mode == 3)
            di = (size_t)((((n & 255) >> 3) << 7) + ((n >> 8) << 3) + (n & 7)) * 256 + k;
        else if (mode == 4)
            di = (size_t)((((n & 255) >> 3) << 7) + 64 + ((n >> 8) << 3) + (n & 7)) * 256 + k;
        else
            di = (size_t)n * R + k;
        dst[di] = (bf16)tile[lx][r];
    }
}

__global__ __launch_bounds__(256) void prep(
    const void* __restrict__ x,
    const void* __restrict__ Wq, const void* __restrict__ bq,
    const void* __restrict__ Wk, const void* __restrict__ bk,
    const void* __restrict__ Wv, const void* __restrict__ bv,
    const void* __restrict__ Wo, const void* __restrict__ bo,
    bf16* __restrict__ xb, bf16* __restrict__ WTI, bf16* __restrict__ WoT,
    bf16* __restrict__ bqkv, bf16* __restrict__ bob)
{
    __shared__ float tile[32][33];
    __shared__ int sflag;
    int tid = threadIdx.x;
    if (tid == 0) sflag = 0;
    __syncthreads();
    {
        float v = fabsf((float)((const bf16*)x)[2 * tid]);
        if (!(v < 1e4f)) sflag = 1;   // benign race, all writers store 1
    }
    __syncthreads();
    int f = sflag;
    int b = blockIdx.x;

    if (b < 4096) {                               // convert x
        int i = b * 256 + tid;
        bf16x4 o;
        if (f) { f32x4 v = ((const f32x4*)x)[i]; for (int e = 0; e < 4; e++) o[e] = (bf16)v[e]; }
        else   { o = ((const bf16x4*)x)[i]; }
        ((bf16x4*)xb)[i] = o;
    } else if (b < 4121) {                        // biases (WTI-row order)
        int i = (b - 4096) * 256 + tid;
        if (i < 6400) {
            const void* src; bf16* dst = bqkv; int off, woff;
            if (i < 2048) {
                src = bq; off = i;
                int d = off & 255, h = off >> 8;
                woff = ((d >> 3) << 7) + (h << 3) + (d & 7);
            } else if (i < 4096) {
                src = bk; off = i - 2048;
                int d = off & 255, h = off >> 8;
                woff = ((d >> 3) << 7) + 64 + (h << 3) + (d & 7);
            } else if (i < 6144) {
                src = bv; off = i - 4096;
                woff = 4096 + ((off & 255) << 3) + (off >> 8);
            } else {
                src = bo; dst = bob; off = i - 6144; woff = off;
            }
            float v = f ? ((const float*)src)[off] : (float)((const bf16*)src)[off];
            dst[woff] = (bf16)v;
        }
        __syncthreads();                          // match transpose barrier count
    } else if (b < 5657) {                        // Wq/Wk/Wv -> WTI
        int idx = b - 4121;                       // 0..1535
        int tx = idx & 63, rest = idx >> 6;
        int ty = rest & 7, tz = rest >> 3;
        const void* src = (tz == 0) ? Wq : (tz == 1) ? Wk : Wv;
        int mode = (tz == 0) ? 3 : (tz == 1) ? 4 : 2;
        transpose_body(src, WTI, 256, 2048, tx * 32, ty * 32, f, mode, tile);
    } else {                                      // Wo -> WoT (K d-major)
        int idx = b - 5657;                       // 0..511
        int tx = idx & 7, ty = idx >> 3;
        transpose_body(Wo, WoT, 2048, 256, tx * 32, ty * 32, f, 1, tile);
    }
}

// ---------------------------------------------------------------------------
// Kernel 1: v = x @ Wv + bv  (d-major cols). Verified kernel, unchanged.
// ---------------------------------------------------------------------------
__global__ __launch_bounds__(256) void v_proj(
    const bf16* __restrict__ X, const bf16* __restrict__ WT,
    const bf16* __restrict__ bI, bf16* __restrict__ vout)
{
    __shared__ char smem[36864];               // union: As+Bs (32K) / epi (36K)
    bf16* As = (bf16*)smem;                    // 128*64
    bf16* Bs = (bf16*)(smem + 16384);          // 128*64
    int m0 = blockIdx.y * 128, n0 = blockIdx.x * 128;
    int tid = threadIdx.x, wave = tid >> 6, lane = tid & 63;
    int wm = (wave >> 1) * 64, wn = (wave & 1) * 64;
    int mrow = lane & 15, quad = lane >> 4;
    int lrow8 = lane >> 3, lslot = lane & 7;

    f32x4 acc[4][4] = {};
    for (int k0 = 0; k0 < D_; k0 += 64) {
        __syncthreads();
        for (int i = 0; i < 4; i++) {
            int rbase = wave * 32 + i * 8;
            int row = rbase + lrow8;
            int gc = lslot ^ (row & 7);
            GLDS16(&X[(size_t)(m0 + row) * D_ + k0 + gc * 8], &As[rbase * 64]);
            GLDS16(&WT[(size_t)(n0 + row) * D_ + k0 + gc * 8], &Bs[rbase * 64]);
        }
        __syncthreads();
        for (int kk = 0; kk < 64; kk += 32) {
            int slot = (((kk >> 3) + quad) ^ (mrow & 7)) * 8;
            bf16x8 af[4], bfv[4];
            for (int mt = 0; mt < 4; mt++)
                af[mt] = *(const bf16x8*)&As[(wm + mt * 16 + mrow) * 64 + slot];
            for (int nt = 0; nt < 4; nt++)
                bfv[nt] = *(const bf16x8*)&Bs[(wn + nt * 16 + mrow) * 64 + slot];
            for (int mt = 0; mt < 4; mt++)
                for (int nt = 0; nt < 4; nt++)
                    acc[mt][nt] = __builtin_amdgcn_mfma_f32_16x16x32_bf16(
                        bfv[nt], af[mt], acc[mt][nt], 0, 0, 0);
        }
    }

    __syncthreads();
    bf16* ep = (bf16*)smem + wave * (64 * 72);
    for (int mt = 0; mt < 4; mt++) {
        for (int nt = 0; nt < 4; nt++) {
            int col = n0 + wn + nt * 16 + quad * 4;
            bf16x4 bb = *(const bf16x4*)&bI[col];
            bf16x4 o;
            for (int r = 0; r < 4; r++) o[r] = (bf16)(acc[mt][nt][r] + (float)bb[r]);
            *(bf16x4*)&ep[(mt * 16 + mrow) * 72 + nt * 16 + quad * 4] = o;
        }
    }
    __syncthreads();
    for (int i = 0; i < 8; i++) {
        int r = i * 8 + (lane >> 3);
        int cb = (lane & 7) * 8;
        bf16x8 val = *(const bf16x8*)&ep[r * 72 + cb];
        *(bf16x8*)&vout[(size_t)(m0 + wm + r) * VN + n0 + wn + cb] = val;
    }
}

// ---------------------------------------------------------------------------
// Kernel 2: q/k projection + per-token 8x8 scores + softmax -> P.  v6:
// r8 structure at HALF tokens (32/block, grid 512) and FULL d-sweep --
// every block reads WTI subtiles it=0..31 in the SAME order (phase-locked
// sweep = r8's L2-resident pattern; r9's d-split broke this -> 817 MB FETCH).
// LDS 73 KB (Ws single 8KB/wave [r9-proven chain: vm(0) -> bvv -> lgkm ->
// restage] + qkh stride-288) -> 2 anti-phase blocks/CU fill the barrier
// convoy that left r8 at 55% stall.
// ---------------------------------------------------------------------------
__global__ __launch_bounds__(512, 4) void qk_score(
    const bf16* __restrict__ X, const bf16* __restrict__ WTI,
    const bf16* __restrict__ bI, float* __restrict__ P)
{
    __shared__ bf16 Ws[8][16 * 256];          // 64 KB: per-wave single-buffer B
    __shared__ __align__(16) char qkh[32 * 288];  // 9 KB, stride 288 B (bank-spread)
    int tid = threadIdx.x, wave = tid >> 6, lane = tid & 63;
    int mrow = lane & 15, quad = lane >> 4;
    int h = lane >> 3, g = lane & 7;
    int t0 = blockIdx.x * 32;
    bf16* wsbase = &Ws[0][0];

    // ---- prologue: x-tile 32x256 -> Ws[0..1] (cooperative) ----
#pragma unroll
    for (int i = 0; i < 2; i++) {
        int row = i * 16 + wave * 2 + (lane >> 5);
        int sl = lane & 31;
        int gc = (sl & 24) | ((sl & 7) ^ (row & 7));
        GLDS16(&X[(size_t)(t0 + row) * 256 + gc * 8],
               &wsbase[(i * 16 + wave * 2) * 256]);
    }
    WAIT_VM(0);
    BAR();
    bf16x8 areg[2][8];                        // all 32 tokens, K=256
#pragma unroll
    for (int mt = 0; mt < 2; mt++)
#pragma unroll
        for (int ks = 0; ks < 8; ks++) {
            int arow = mt * 16 + mrow;
            int sl = ks * 4 + quad;
            int ph = (sl & 24) | ((sl & 7) ^ (arow & 7));
            areg[mt][ks] = *(const bf16x8*)&wsbase[arow * 256 + ph * 8];
        }
    WAIT_LGKM0;                               // A lifts retired before Ws reuse
    BAR();

    bf16* wsw = &Ws[wave][0];                 // this wave's private 8KB buffer
    const bf16* wsrc = WTI + (size_t)(wave * 16) * 256;
#define QK_STAGE(GIT) {                                                        \
        const bf16* s_ = wsrc + (size_t)(GIT) * 32768;                         \
        _Pragma("unroll")                                                      \
        for (int j = 0; j < 8; j++) {                                          \
            int row = j * 2 + (lane >> 5);                                     \
            int sl = lane & 31;                                                \
            int gc = (sl & 24) | ((sl & 7) ^ (row & 7));                       \
            GLDS16(&s_[(size_t)row * 256 + gc * 8], &wsw[j * 512]);            \
        } }
    QK_STAGE(0)

    float S[4] = {};

    for (int it = 0; it < 32; it++) {
        WAIT_VM(0);                            // my 8 DMAs for subtile it done
        bf16x8 bvv[8];
#pragma unroll
        for (int ks = 0; ks < 8; ks++) {
            int sl = ks * 4 + quad;
            int ph = (sl & 24) | ((sl & 7) ^ (mrow & 7));
            bvv[ks] = *(const bf16x8*)&wsw[mrow * 256 + ph * 8];
        }
        WAIT_LGKM0;                            // bvv in regs -> buffer free
        SCHEDFENCE();
        if (it < 31) QK_STAGE(it + 1)

        f32x4 acc[2] = {};
#pragma unroll
        for (int ks = 0; ks < 8; ks++)
#pragma unroll
            for (int mt = 0; mt < 2; mt++)
                acc[mt] = __builtin_amdgcn_mfma_f32_16x16x32_bf16(
                    bvv[ks], areg[mt][ks], acc[mt], 0, 0, 0);

        // epilogue -> qkh: token t = mt*16+mrow, granule (wave*4+quad)^((t&7)<<1)
        bf16x4 bb = *(const bf16x4*)&bI[it * 128 + wave * 16 + quad * 4];
#pragma unroll
        for (int mt = 0; mt < 2; mt++) {
            int t = mt * 16 + mrow;
            bf16x4 o;
#pragma unroll
            for (int r = 0; r < 4; r++) o[r] = (bf16)(acc[mt][r] + (float)bb[r]);
            int g8 = (wave * 4 + quad) ^ ((t & 7) << 1);
            *(bf16x4*)(qkh + t * 288 + g8 * 8) = o;
        }
        WAIT_LGKM0;                            // epi writes committed
        BAR();                                 // qkh(it) published to all waves

        // score accumulate: wave owns tokens wave*4..+3; broadcast reads
#pragma unroll
        for (int u = 0; u < 4; u++) {
            int t = wave * 4 + u;
            int s = (t & 7) << 1;
            const char* base = qkh + t * 288;
            bf16x8 qv = *(const bf16x8*)(base + ((h * 2) ^ s) * 8);
            bf16x8 kv = *(const bf16x8*)(base + (((16 + g * 2)) ^ s) * 8);
            float a = 0.f;
#pragma unroll
            for (int e = 0; e < 8; e++) a += (float)qv[e] * (float)kv[e];
            S[u] += a;
        }
        WAIT_LGKM0;                            // score reads retired
        BAR();                                 // before next iter's epi rewrites
    }
#undef QK_STAGE

    // ---- softmax + P write (wave owns tokens wave*4..+3) ----
#pragma unroll
    for (int u = 0; u < 4; u++) {
        int t = t0 + wave * 4 + u;
        float sc = S[u] * 0.0625f;
        float m = sc;
        for (int off = 1; off < 8; off <<= 1) m = fmaxf(m, __shfl_xor(m, off, 8));
        float p = __expf(sc - m);
        float sum = p;
        for (int off = 1; off < 8; off <<= 1) sum += __shfl_xor(sum, off, 8);
        P[(size_t)t * 64 + lane] = p / sum;
    }
}

// ---------------------------------------------------------------------------
// Kernel 3: out = (P @ v) @ Wo' + bo, attnout never in LDS or HBM.
// (Verified r5/r8 kernel, unchanged — P direct.)
// ---------------------------------------------------------------------------
__global__ __launch_bounds__(256) void out_fused(
    const bf16* __restrict__ vb, const bf16* __restrict__ WoT,
    const float* __restrict__ P, const bf16* __restrict__ bob,
    float* __restrict__ outp)
{
    __shared__ bf16 Bs[2][256 * 64];   // 64 KB  Wo' chunk (double)
    __shared__ bf16 Vs[2][32 * 64];    // 8 KB   v chunk (double)
    int m0 = blockIdx.x * 32;
    int tid = threadIdx.x, wave = tid >> 6, lane = tid & 63;
    int wm = (wave >> 1) * 16, wn = (wave & 1) * 128;
    int mrow = lane & 15, quad = lane >> 4;
    int t = wm + mrow, ts = t & 7;
    int sl8 = lane >> 3, sl = lane & 7;

    float Pv[64];
    {
        const float* pr = P + (size_t)(m0 + t) * 64;
#pragma unroll
        for (int j = 0; j < 16; j++) {
            f32x4 v4 = *(const f32x4*)&pr[j * 4];
            Pv[4 * j + 0] = v4[0]; Pv[4 * j + 1] = v4[1];
            Pv[4 * j + 2] = v4[2]; Pv[4 * j + 3] = v4[3];
        }
    }

    f32x4 acc[8] = {};
    {   // prologue: stage chunk 0
        int tt = (wave << 3) + sl8;
        GLDS16(&vb[(size_t)(m0 + tt) * VN + ((sl ^ (tt & 7)) << 3)],
               &Vs[0][wave * 512]);
#pragma unroll
        for (int i = 0; i < 8; i++) {
            int n = (wave << 6) + (i << 3) + sl8;
            GLDS16(&WoT[(size_t)n * HD + ((sl ^ (n & 7)) << 3)],
                   &Bs[0][((wave << 6) + (i << 3)) << 6]);
        }
    }

    for (int c = 0; c < 32; c++) {
        __syncthreads();               // buf[c&1] resident (barrier drains vmcnt)
        if (c < 31) {
            int cc = c + 1, bb = cc & 1;
            int tt = (wave << 3) + sl8;
            GLDS16(&vb[(size_t)(m0 + tt) * VN + cc * 64 + ((sl ^ (tt & 7)) << 3)],
                   &Vs[bb][wave * 512]);
#pragma unroll
            for (int i = 0; i < 8; i++) {
                int n = (wave << 6) + (i << 3) + sl8;
                GLDS16(&WoT[(size_t)n * HD + cc * 64 + ((sl ^ (n & 7)) << 3)],
                       &Bs[bb][((wave << 6) + (i << 3)) << 6]);
            }
        }
        const bf16* Vb = Vs[c & 1];
        const bf16* Bb = Bs[c & 1];

        bf16x8 vf0 = *(const bf16x8*)&Vb[(t << 6) + ((quad ^ ts) << 3)];
        bf16x8 vf1 = *(const bf16x8*)&Vb[(t << 6) + (((quad + 4) ^ ts) << 3)];
        float v0f[8], v1f[8];
#pragma unroll
        for (int e = 0; e < 8; e++) { v0f[e] = (float)vf0[e]; v1f[e] = (float)vf1[e]; }
        bf16x8 af0, af1;
#pragma unroll
        for (int hh = 0; hh < 8; hh++) {
            float a0 = 0.f, a1 = 0.f;
#pragma unroll
            for (int gg = 0; gg < 8; gg++) {
                a0 += Pv[hh * 8 + gg] * v0f[gg];
                a1 += Pv[hh * 8 + gg] * v1f[gg];
            }
            af0[hh] = (bf16)a0; af1[hh] = (bf16)a1;
        }
#pragma unroll
        for (int nt = 0; nt < 8; nt++) {
            bf16x8 bv = *(const bf16x8*)&Bb[(wn + nt * 16 + mrow) * 64
                            + ((quad ^ (mrow & 7)) << 3)];
            acc[nt] = __builtin_amdgcn_mfma_f32_16x16x32_bf16(bv, af0, acc[nt], 0, 0, 0);
        }
#pragma unroll
        for (int nt = 0; nt < 8; nt++) {
            bf16x8 bv = *(const bf16x8*)&Bb[(wn + nt * 16 + mrow) * 64
                            + (((4 + quad) ^ (mrow & 7)) << 3)];
            acc[nt] = __builtin_amdgcn_mfma_f32_16x16x32_bf16(bv, af1, acc[nt], 0, 0, 0);
        }
    }

    int row = m0 + wm + mrow;
#pragma unroll
    for (int nt = 0; nt < 8; nt++) {
        int col = wn + nt * 16 + quad * 4;
        bf16x4 bb = *(const bf16x4*)&bob[col];
        f32x4 o;
        for (int r = 0; r < 4; r++) o[r] = acc[nt][r] + (float)bb[r];
        *(f32x4*)&outp[(size_t)row * D_ + col] = o;
    }
}

// ---------------------------------------------------------------------------
extern "C" void kernel_launch(void* const* d_in, const int* in_sizes, int n_in,
                              void* d_out, int out_size, void* d_ws, size_t ws_size,
                              hipStream_t stream)
{
    const void* x  = d_in[0];
    const void* Wq = d_in[1];
    const void* bq = d_in[2];
    const void* Wk = d_in[3];
    const void* bk = d_in[4];
    const void* Wv = d_in[5];
    const void* bv = d_in[6];
    const void* Wo = d_in[7];
    const void* bo = d_in[8];
    float* out = (float*)d_out;

    char* ws = (char*)d_ws;
    bf16*  vbuf = (bf16*)ws;                      // 16384*2048*2 = 67108864
    bf16*  WTI  = (bf16*)(ws + 67108864);         // 6144*256*2   = 3145728
    bf16*  WoT  = (bf16*)(ws + 70254592);         // 256*2048*2   = 1048576
    bf16*  xb   = (bf16*)(ws + 71303168);         // 16384*256*2  = 8388608
    bf16*  bqkv = (bf16*)(ws + 79691776);         // 6144*2       = 12288
    bf16*  bob  = (bf16*)(ws + 79704064);         // 512
    float* Pbuf = (float*)(ws + 79704576);        // 16384*64*4   = 4194304

    prep<<<6169, 256, 0, stream>>>(x, Wq, bq, Wk, bk, Wv, bv, Wo, bo,
                                   xb, WTI, WoT, bqkv, bob);
    qk_score<<<512, 512, 0, stream>>>(xb, WTI, bqkv, Pbuf);
    v_proj<<<dim3(16, 128), 256, 0, stream>>>(xb, WTI + 4096 * 256, bqkv + 4096, vbuf);
    out_fused<<<512, 256, 0, stream>>>(vbuf, WoT, Pbuf, bob, out);
}